// Round 1
// baseline (5540.327 us; speedup 1.0000x reference)
//
#include <hip/hip_runtime.h>

// 3-layer LSTM, B=256, T=2048, H=128.
// Design: all 3 layers run CONCURRENTLY in one 256-thread block, skewed by one
// 16-step chunk (layer L processes chunk s-L at stage s). h handoff via LDS
// (no global gbuf at all). 130 stages x 16 steps = 2080 serial steps vs 6144.
// Per wave: 2 unit-groups x 3 layers; rec weight frags resident (384 VGPR).
// Gate math: one gate per lane-quadrant q (i,f,g,o = q0..q3), unified
// act = Aq + Bq*rcp(1+exp(me*pre)), combined with 3 shfl_xor. v_rcp not div.
// Proj (Wih*h) GEMM done per-stage, B-frags streamed from global (L2-hot).
// Watch: VGPR_Count (budget ~470/512), absmax (~5e-4 expected).

#define HDIM 128
#define TDIM 2048
#define BDIM 256
#define NT 256          // 4 waves
#define XGP 20          // fp32 dword pitch per gate row in xg_s

typedef _Float16 half8_t __attribute__((ext_vector_type(8)));
typedef float f32x4 __attribute__((ext_vector_type(4)));

__device__ __forceinline__ f32x4 mfma16(half8_t a, half8_t b, f32x4 c) {
    return __builtin_amdgcn_mfma_f32_16x16x32_f16(a, b, c, 0, 0, 0);
}

// Workgroup barrier WITHOUT vmcnt(0) drain: LDS visibility only.
__device__ __forceinline__ void fast_barrier() {
    asm volatile("s_waitcnt lgkmcnt(0)\n\ts_barrier" ::: "memory");
}

// One-time fp32 -> fp16 weight conversion. Segments of 65536: [Whh0,Wih1,Whh1,Wih2,Whh2]
__global__ __launch_bounds__(256)
void convert_w(const float* __restrict__ Whh0, const float* __restrict__ Wih1,
               const float* __restrict__ Whh1, const float* __restrict__ Wih2,
               const float* __restrict__ Whh2, _Float16* __restrict__ dst) {
    int i = blockIdx.x * 256 + threadIdx.x;
    int seg = i >> 16, off = i & 65535;
    const float* s = (seg == 0) ? Whh0 : (seg == 1) ? Wih1 : (seg == 2) ? Whh1
                   : (seg == 3) ? Wih2 : Whh2;
    dst[i] = (_Float16)s[off];
}

// 16 MFMAs for one (layer, 16-unit group): 4 gate chains x K=128.
// All A rows identical (broadcast h) -> result in [0] of each acc.
// selout_ = this lane's gate (q) pre-activation contribution.
#define RECG(Lc, gc, A0_,A1_,A2_,A3_, selout_) { \
    f32x4 z0 = {0.f,0.f,0.f,0.f}; f32x4 z1 = z0, z2 = z0, z3 = z0; \
    z0 = mfma16(A0_, whf[Lc][gc][0][0], z0); \
    z0 = mfma16(A1_, whf[Lc][gc][0][1], z0); \
    z0 = mfma16(A2_, whf[Lc][gc][0][2], z0); \
    z0 = mfma16(A3_, whf[Lc][gc][0][3], z0); \
    z1 = mfma16(A0_, whf[Lc][gc][1][0], z1); \
    z1 = mfma16(A1_, whf[Lc][gc][1][1], z1); \
    z1 = mfma16(A2_, whf[Lc][gc][1][2], z1); \
    z1 = mfma16(A3_, whf[Lc][gc][1][3], z1); \
    z2 = mfma16(A0_, whf[Lc][gc][2][0], z2); \
    z2 = mfma16(A1_, whf[Lc][gc][2][1], z2); \
    z2 = mfma16(A2_, whf[Lc][gc][2][2], z2); \
    z2 = mfma16(A3_, whf[Lc][gc][2][3], z2); \
    z3 = mfma16(A0_, whf[Lc][gc][3][0], z3); \
    z3 = mfma16(A1_, whf[Lc][gc][3][1], z3); \
    z3 = mfma16(A2_, whf[Lc][gc][3][2], z3); \
    z3 = mfma16(A3_, whf[Lc][gc][3][3], z3); \
    float s0_ = qb1 ? z1[0] : z0[0]; \
    float s1_ = qb1 ? z3[0] : z2[0]; \
    selout_ = qb2 ? s1_ : s0_; }

// One-gate-per-quadrant activation + cross-quadrant combine.
// q0=i, q1=f, q2=g, q3=o.  act = Aq + Bq*rcp(1+exp(me*pre)):
//   sigmoid (q!=2): me=-1, Aq=0, Bq=1 ;  tanh (q==2): me=2, Aq=1, Bq=-2.
// xor32: q0<-g, q1<-o ; xor16 of act: q0<-f ; xor16 of v: q0<-o.
// Only q0 lanes have a valid c/h; others compute bounded garbage (never read).
#define GATECOMB(pre_, cr_, hout_) { \
    float e_ = __expf(me * (pre_)); \
    float r_ = __builtin_amdgcn_rcpf(1.0f + e_); \
    float a_ = fmaf(Bq, r_, Aq); \
    float v_ = __shfl_xor(a_, 32); \
    float p_ = a_ * v_;            /* q0: i*g */ \
    float f_ = __shfl_xor(a_, 16); /* q0: f   */ \
    float o_ = __shfl_xor(v_, 16); /* q0: o   */ \
    (cr_) = fmaf(f_, (cr_), p_); \
    float e2_ = __expf(2.0f * (cr_)); \
    float tc_ = fmaf(-2.0f, __builtin_amdgcn_rcpf(1.0f + e2_), 1.0f); \
    (hout_) = o_ * tc_; }

// One recurrence step for layer Lc: read h(t-1) row RP_, write h(t) row WP_.
#define STEPL(Lc, RP_, WP_, PRE0_, PRE1_) { \
    const _Float16* rp_ = (RP_); \
    half8_t A0_ = *(const half8_t*)(rp_ + kb); \
    half8_t A1_ = *(const half8_t*)(rp_ + 32 + kb); \
    half8_t A2_ = *(const half8_t*)(rp_ + 64 + kb); \
    half8_t A3_ = *(const half8_t*)(rp_ + 96 + kb); \
    { float sel_; RECG(Lc, 0, A0_,A1_,A2_,A3_, sel_); \
      float h_; GATECOMB((PRE0_), cst[Lc][0], h_); \
      if (q == 0) (WP_)[wv*32 + n16] = (_Float16)h_; } \
    { float sel_; RECG(Lc, 1, A0_,A1_,A2_,A3_, sel_); \
      float h_; GATECOMB((PRE1_), cst[Lc][1], h_); \
      if (q == 0) (WP_)[wv*32 + 16 + n16] = (_Float16)h_; } }

// Per-stage proj GEMM: xg_s[XGI][gate][0..15] += nothing (overwrite), for the
// 16 timesteps of the source chunk HSRC (16 rows x 128). Wave wv owns gate
// tiles 8*wv..8*wv+7. B-frags streamed from global (L2-resident fp16 Wih).
#define PROJ(XGI, HSRC, WIH) { \
    const _Float16* hr_ = &(HSRC)[n16][0]; \
    half8_t X0 = *(const half8_t*)(hr_ + kb); \
    half8_t X1 = *(const half8_t*)(hr_ + 32 + kb); \
    half8_t X2 = *(const half8_t*)(hr_ + 64 + kb); \
    half8_t X3 = *(const half8_t*)(hr_ + 96 + kb); \
    _Pragma("unroll 4") \
    for (int j = 0; j < 8; ++j) { \
      const int gp_ = (wv*8 + j)*16 + n16; \
      const _Float16* wp_ = (WIH) + (size_t)gp_*HDIM + kb; \
      half8_t B0 = *(const half8_t*)(wp_); \
      half8_t B1 = *(const half8_t*)(wp_ + 32); \
      half8_t B2 = *(const half8_t*)(wp_ + 64); \
      half8_t B3 = *(const half8_t*)(wp_ + 96); \
      f32x4 a_ = {0.f,0.f,0.f,0.f}; \
      a_ = mfma16(X0, B0, a_); a_ = mfma16(X1, B1, a_); \
      a_ = mfma16(X2, B2, a_); a_ = mfma16(X3, B3, a_); \
      *(f32x4*)&xg_s[XGI][gp_*XGP + q*4] = a_; \
    } }

__global__ __launch_bounds__(NT, 1)
void lstm3_kernel(const float* __restrict__ x,   const float* __restrict__ Wih0,
                  const float* __restrict__ bih0, const float* __restrict__ bhh0,
                  const float* __restrict__ bih1, const float* __restrict__ bhh1,
                  const float* __restrict__ bih2, const float* __restrict__ bhh2,
                  const float* __restrict__ fc1w, const float* __restrict__ fc1b,
                  const float* __restrict__ fc2w, const float* __restrict__ fc2b,
                  float* __restrict__ out, const _Float16* __restrict__ wbuf)
{
    // h windows: [layer][chunk parity][step][unit]
    __shared__ __align__(16) _Float16 hw[3][2][16][HDIM];
    // input contributions for layers 1,2, current chunk: [layer-1][gate*XGP+tt]
    __shared__ __align__(16) float xg_s[2][512 * XGP];
    __shared__ float x_s[16];
    __shared__ float z_s[64];

    const int tid = threadIdx.x;
    const int ln  = tid & 63;
    const int wv  = tid >> 6;        // wave 0..3
    const int n16 = ln & 15;         // unit-within-group / MFMA column
    const int q   = ln >> 4;         // quadrant = gate index (i,f,g,o)
    const int kb  = q * 8;           // k-offset within a 32-block
    const bool qb1 = q & 1, qb2 = q & 2;
    const int b = blockIdx.x;

    // zero h windows (h(-1) = 0 for every layer)
    { int* p = (int*)hw; for (int i = tid; i < 6144; i += NT) p[i] = 0; }

    // resident recurrent-weight fragments: whf[layer][group][gate][kblk]
    half8_t whf[3][2][4][4];
    {
        const _Float16* wrec[3] = { wbuf, wbuf + (size_t)2*65536, wbuf + (size_t)4*65536 };
#pragma unroll
        for (int L = 0; L < 3; ++L)
#pragma unroll
            for (int g = 0; g < 2; ++g)
#pragma unroll
                for (int tau = 0; tau < 4; ++tau)
#pragma unroll
                    for (int kk = 0; kk < 4; ++kk)
                        whf[L][g][tau][kk] = *(const half8_t*)(wrec[L]
                            + (size_t)(tau*HDIM + wv*32 + g*16 + n16)*HDIM + kk*32 + kb);
    }
    const _Float16* wih1p = wbuf + (size_t)1*65536;
    const _Float16* wih2p = wbuf + (size_t)3*65536;

    // per-lane bias (this lane's gate only) and layer-0 input weight
    float bsv[3][2]; float w0v[2];
    {
        const float* bihs[3] = {bih0, bih1, bih2};
        const float* bhhs[3] = {bhh0, bhh1, bhh2};
#pragma unroll
        for (int L = 0; L < 3; ++L)
#pragma unroll
            for (int g = 0; g < 2; ++g) {
                int gate = q*HDIM + wv*32 + g*16 + n16;
                bsv[L][g] = bihs[L][gate] + bhhs[L][gate];
            }
#pragma unroll
        for (int g = 0; g < 2; ++g) w0v[g] = Wih0[q*HDIM + wv*32 + g*16 + n16];
    }

    const float me = (q == 2) ? 2.0f : -1.0f;
    const float Aq = (q == 2) ? 1.0f : 0.0f;
    const float Bq = (q == 2) ? -2.0f : 1.0f;

    const int xgb0 = (q*HDIM + wv*32 + n16) * XGP;   // gate row base, group 0
    const int xgb1 = xgb0 + 16 * XGP;                // group 1

    float cst[3][2] = {{0.f,0.f},{0.f,0.f},{0.f,0.f}};
    const float* xb = x + (size_t)b * TDIM;

    // ===== chunk-skewed 3-layer pipeline: stage s: L0 on chunk s, L1 on s-1, L2 on s-2
#pragma unroll 1
    for (int s = 0; s < 130; ++s) {
        const int par = s & 1;
        const bool act0 = (s < 128), act1 = (s >= 1) && (s < 129), act2 = (s >= 2);

        fast_barrier();   // prev stage's LDS reads done; proj/x_s may overwrite

        if (act0 && tid < 16) x_s[tid] = xb[s*16 + tid];
        // proj for L1 chunk s-1 from h0(chunk s-1) = hw[0][par^1] (full, written last stage)
        if (act1) PROJ(0, hw[0][par^1], wih1p);
        // proj for L2 chunk s-2 from h1(chunk s-2) = hw[1][par]
        if (act2) PROJ(1, hw[1][par], wih2p);

        fast_barrier();   // proj + x_s visible

#pragma unroll 1
        for (int tt = 0; tt < 16; ++tt) {
            if (tt) fast_barrier();
            // h(t-1) row / h(t) row per layer (cur-buf parity: L0,L2=par; L1=par^1)
            const _Float16* r0p = tt ? hw[0][par][tt-1]   : hw[0][par^1][15];
            _Float16*       q0p = hw[0][par][tt];
            const _Float16* r1p = tt ? hw[1][par^1][tt-1] : hw[1][par][15];
            _Float16*       q1p = hw[1][par^1][tt];
            const _Float16* r2p = tt ? hw[2][par][tt-1]   : hw[2][par^1][15];
            _Float16*       q2p = hw[2][par][tt];
            const float xt = x_s[tt];

            if (act0 && act1 && act2) {
                // steady state: one basic block so the scheduler interleaves all 3 layers
                STEPL(0, r0p, q0p, sel_ + fmaf(xt, w0v[0], bsv[0][0]),
                                   sel_ + fmaf(xt, w0v[1], bsv[0][1]));
                STEPL(1, r1p, q1p, sel_ + xg_s[0][xgb0 + tt] + bsv[1][0],
                                   sel_ + xg_s[0][xgb1 + tt] + bsv[1][1]);
                STEPL(2, r2p, q2p, sel_ + xg_s[1][xgb0 + tt] + bsv[2][0],
                                   sel_ + xg_s[1][xgb1 + tt] + bsv[2][1]);
            } else {
                if (act0) STEPL(0, r0p, q0p, sel_ + fmaf(xt, w0v[0], bsv[0][0]),
                                             sel_ + fmaf(xt, w0v[1], bsv[0][1]));
                if (act1) STEPL(1, r1p, q1p, sel_ + xg_s[0][xgb0 + tt] + bsv[1][0],
                                             sel_ + xg_s[0][xgb1 + tt] + bsv[1][1]);
                if (act2) STEPL(2, r2p, q2p, sel_ + xg_s[1][xgb0 + tt] + bsv[2][0],
                                             sel_ + xg_s[1][xgb1 + tt] + bsv[2][1]);
            }
        }
    }

    // ---- FC head: final h2 (t=2047) = hw[2][127&1=1][15] ----
    fast_barrier();
    if (tid < 64) {
        const float* w = fc1w + tid * HDIM;
        float sacc = fc1b[tid];
#pragma unroll
        for (int k = 0; k < HDIM; ++k) sacc += w[k] * (float)hw[2][1][15][k];
        z_s[tid] = fmaxf(sacc, 0.0f);
    }
    __syncthreads();
    if (tid < 5) {
        const float* w = fc2w + tid * 64;
        float sacc = fc2b[tid];
#pragma unroll
        for (int k = 0; k < 64; ++k) sacc += w[k] * z_s[k];
        out[b * 5 + tid] = sacc;
    }
}

extern "C" void kernel_launch(void* const* d_in, const int* in_sizes, int n_in,
                              void* d_out, int out_size, void* d_ws, size_t ws_size,
                              hipStream_t stream) {
    (void)in_sizes; (void)n_in; (void)out_size; (void)ws_size;
    const float* x    = (const float*)d_in[0];
    const float* Wih0 = (const float*)d_in[1];
    const float* Whh0 = (const float*)d_in[2];
    const float* bih0 = (const float*)d_in[3];
    const float* bhh0 = (const float*)d_in[4];
    const float* Wih1 = (const float*)d_in[5];
    const float* Whh1 = (const float*)d_in[6];
    const float* bih1 = (const float*)d_in[7];
    const float* bhh1 = (const float*)d_in[8];
    const float* Wih2 = (const float*)d_in[9];
    const float* Whh2 = (const float*)d_in[10];
    const float* bih2 = (const float*)d_in[11];
    const float* bhh2 = (const float*)d_in[12];
    const float* fc1w = (const float*)d_in[13];
    const float* fc1b = (const float*)d_in[14];
    const float* fc2w = (const float*)d_in[15];
    const float* fc2b = (const float*)d_in[16];
    float* out = (float*)d_out;

    _Float16* wbuf = (_Float16*)d_ws;   // fp16 weights (640 KB); no gbuf needed anymore

    hipLaunchKernelGGL(convert_w, dim3(1280), dim3(256), 0, stream,
                       Whh0, Wih1, Whh1, Wih2, Whh2, wbuf);
    hipLaunchKernelGGL(lstm3_kernel, dim3(BDIM), dim3(NT), 0, stream,
                       x, Wih0, bih0, bhh0, bih1, bhh1, bih2, bhh2,
                       fc1w, fc1b, fc2w, fc2b, out, wbuf);
}

// Round 2
// 3542.224 us; speedup vs baseline: 1.5641x; 1.5641x over previous
//
#include <hip/hip_runtime.h>

// 3-layer LSTM, B=256, T=2048, H=128 — chunk-skewed 3-layer pipeline, v2.
// R1 post-mortem: whf needed 384 VGPRs > 256 architectural max -> compiler
// demoted weights (VGPR_Count=236), 1 wave/SIMD, latency-bound, 5540us.
// v2: 8 waves x ONE 16-unit group each -> whf[3][4][4] = 192 VGPRs resident,
// 2 waves/SIMD TLP. Same pipeline skew (layer L does chunk s-L at stage s),
// 130 stages x 16 steps = 2080 serial steps. h handoff via LDS, no gbuf.
// Gate-per-quadrant activation (i,f,g,o = q0..q3) + 3 shfl_xor combine.
// Watch: VGPR_Count ~250 (256+scratch = spill failure signature).

#define HDIM 128
#define TDIM 2048
#define BDIM 256
#define NT 512          // 8 waves
#define XGP 20          // fp32 dword pitch per gate row in xg_s (must be %4==0)

typedef _Float16 half8_t __attribute__((ext_vector_type(8)));
typedef float f32x4 __attribute__((ext_vector_type(4)));

__device__ __forceinline__ f32x4 mfma16(half8_t a, half8_t b, f32x4 c) {
    return __builtin_amdgcn_mfma_f32_16x16x32_f16(a, b, c, 0, 0, 0);
}

// Workgroup barrier WITHOUT vmcnt(0) drain: LDS visibility only.
__device__ __forceinline__ void fast_barrier() {
    asm volatile("s_waitcnt lgkmcnt(0)\n\ts_barrier" ::: "memory");
}

// One-time fp32 -> fp16 weight conversion. Segments of 65536: [Whh0,Wih1,Whh1,Wih2,Whh2]
__global__ __launch_bounds__(256)
void convert_w(const float* __restrict__ Whh0, const float* __restrict__ Wih1,
               const float* __restrict__ Whh1, const float* __restrict__ Wih2,
               const float* __restrict__ Whh2, _Float16* __restrict__ dst) {
    int i = blockIdx.x * 256 + threadIdx.x;
    int seg = i >> 16, off = i & 65535;
    const float* s = (seg == 0) ? Whh0 : (seg == 1) ? Wih1 : (seg == 2) ? Whh1
                   : (seg == 3) ? Wih2 : Whh2;
    dst[i] = (_Float16)s[off];
}

// 16 MFMAs for one layer's 16-unit group: 4 gate chains x K=128.
// All A rows identical (broadcast h) -> result in [0] of each acc.
// selout_ = this lane's gate (q) pre-activation contribution.
#define RECG(Lc, A0_,A1_,A2_,A3_, selout_) { \
    f32x4 z0 = {0.f,0.f,0.f,0.f}; f32x4 z1 = z0, z2 = z0, z3 = z0; \
    z0 = mfma16(A0_, whf[Lc][0][0], z0); \
    z0 = mfma16(A1_, whf[Lc][0][1], z0); \
    z0 = mfma16(A2_, whf[Lc][0][2], z0); \
    z0 = mfma16(A3_, whf[Lc][0][3], z0); \
    z1 = mfma16(A0_, whf[Lc][1][0], z1); \
    z1 = mfma16(A1_, whf[Lc][1][1], z1); \
    z1 = mfma16(A2_, whf[Lc][1][2], z1); \
    z1 = mfma16(A3_, whf[Lc][1][3], z1); \
    z2 = mfma16(A0_, whf[Lc][2][0], z2); \
    z2 = mfma16(A1_, whf[Lc][2][1], z2); \
    z2 = mfma16(A2_, whf[Lc][2][2], z2); \
    z2 = mfma16(A3_, whf[Lc][2][3], z2); \
    z3 = mfma16(A0_, whf[Lc][3][0], z3); \
    z3 = mfma16(A1_, whf[Lc][3][1], z3); \
    z3 = mfma16(A2_, whf[Lc][3][2], z3); \
    z3 = mfma16(A3_, whf[Lc][3][3], z3); \
    float s0_ = qb1 ? z1[0] : z0[0]; \
    float s1_ = qb1 ? z3[0] : z2[0]; \
    selout_ = qb2 ? s1_ : s0_; }

// One-gate-per-quadrant activation + cross-quadrant combine.
// q0=i, q1=f, q2=g, q3=o.  act = Aq + Bq*rcp(1+exp(me*pre)):
//   sigmoid (q!=2): me=-1, Aq=0, Bq=1 ;  tanh (q==2): me=2, Aq=1, Bq=-2.
// xor32: q0<-g, q1<-o ; xor16 of act: q0<-f ; xor16 of v: q0<-o.
// Only q0 lanes have a valid c/h; others compute bounded garbage (never read).
#define GATECOMB(pre_, cr_, hout_) { \
    float e_ = __expf(me * (pre_)); \
    float r_ = __builtin_amdgcn_rcpf(1.0f + e_); \
    float a_ = fmaf(Bq, r_, Aq); \
    float v_ = __shfl_xor(a_, 32); \
    float p_ = a_ * v_;            /* q0: i*g */ \
    float f_ = __shfl_xor(a_, 16); /* q0: f   */ \
    float o_ = __shfl_xor(v_, 16); /* q0: o   */ \
    (cr_) = fmaf(f_, (cr_), p_); \
    float e2_ = __expf(2.0f * (cr_)); \
    float tc_ = fmaf(-2.0f, __builtin_amdgcn_rcpf(1.0f + e2_), 1.0f); \
    (hout_) = o_ * tc_; }

// One recurrence step for layer Lc: read h(t-1) row RP_, write h(t) row WP_.
#define STEPL(Lc, RP_, WP_, PRE_) { \
    const _Float16* rp_ = (RP_); \
    half8_t A0_ = *(const half8_t*)(rp_ + kb); \
    half8_t A1_ = *(const half8_t*)(rp_ + 32 + kb); \
    half8_t A2_ = *(const half8_t*)(rp_ + 64 + kb); \
    half8_t A3_ = *(const half8_t*)(rp_ + 96 + kb); \
    float sel_; RECG(Lc, A0_,A1_,A2_,A3_, sel_); \
    float h_; GATECOMB((PRE_), cst[Lc], h_); \
    if (q == 0) (WP_)[wv*16 + n16] = (_Float16)h_; }

// Per-stage proj GEMM for the 16 timesteps of source chunk HSRC (16 x 128).
// 32 output tiles (512 gate rows / 16); wave wv owns tiles 4wv..4wv+3.
// B-frags streamed from global (L2-resident fp16 Wih).
#define PROJ(XGI, HSRC, WIH) { \
    const _Float16* hr_ = &(HSRC)[n16][0]; \
    half8_t X0 = *(const half8_t*)(hr_ + kb); \
    half8_t X1 = *(const half8_t*)(hr_ + 32 + kb); \
    half8_t X2 = *(const half8_t*)(hr_ + 64 + kb); \
    half8_t X3 = *(const half8_t*)(hr_ + 96 + kb); \
    _Pragma("unroll") \
    for (int j = 0; j < 4; ++j) { \
      const int gp_ = (wv*4 + j)*16 + n16; \
      const _Float16* wp_ = (WIH) + (size_t)gp_*HDIM + kb; \
      half8_t B0 = *(const half8_t*)(wp_); \
      half8_t B1 = *(const half8_t*)(wp_ + 32); \
      half8_t B2 = *(const half8_t*)(wp_ + 64); \
      half8_t B3 = *(const half8_t*)(wp_ + 96); \
      f32x4 a_ = {0.f,0.f,0.f,0.f}; \
      a_ = mfma16(X0, B0, a_); a_ = mfma16(X1, B1, a_); \
      a_ = mfma16(X2, B2, a_); a_ = mfma16(X3, B3, a_); \
      *(f32x4*)&xg_s[XGI][gp_*XGP + q*4] = a_; \
    } }

__global__ __launch_bounds__(NT, 2)
void lstm3_kernel(const float* __restrict__ x,   const float* __restrict__ Wih0,
                  const float* __restrict__ bih0, const float* __restrict__ bhh0,
                  const float* __restrict__ bih1, const float* __restrict__ bhh1,
                  const float* __restrict__ bih2, const float* __restrict__ bhh2,
                  const float* __restrict__ fc1w, const float* __restrict__ fc1b,
                  const float* __restrict__ fc2w, const float* __restrict__ fc2b,
                  float* __restrict__ out, const _Float16* __restrict__ wbuf)
{
    // h windows: [layer][chunk parity][step][unit]
    __shared__ __align__(16) _Float16 hw[3][2][16][HDIM];
    // input contributions for layers 1,2, current chunk: [layer-1][gate*XGP+tt]
    __shared__ __align__(16) float xg_s[2][512 * XGP];
    __shared__ float x_s[16];
    __shared__ float z_s[64];

    const int tid = threadIdx.x;
    const int ln  = tid & 63;
    const int wv  = tid >> 6;        // wave 0..7 -> owns units [16wv,16wv+16) all layers
    const int n16 = ln & 15;         // unit-within-group / MFMA column
    const int q   = ln >> 4;         // quadrant = gate index (i,f,g,o)
    const int kb  = q * 8;           // k-offset within a 32-block
    const bool qb1 = q & 1, qb2 = q & 2;
    const int b = blockIdx.x;

    // zero h windows (h(-1) = 0 for every layer)
    { int* p = (int*)hw; for (int i = tid; i < 6144; i += NT) p[i] = 0; }

    // resident recurrent-weight fragments: whf[layer][gate][kblk] = 192 VGPRs
    half8_t whf[3][4][4];
    {
        const _Float16* wrec[3] = { wbuf, wbuf + (size_t)2*65536, wbuf + (size_t)4*65536 };
#pragma unroll
        for (int L = 0; L < 3; ++L)
#pragma unroll
            for (int tau = 0; tau < 4; ++tau)
#pragma unroll
                for (int kk = 0; kk < 4; ++kk)
                    whf[L][tau][kk] = *(const half8_t*)(wrec[L]
                        + (size_t)(tau*HDIM + wv*16 + n16)*HDIM + kk*32 + kb);
    }
    const _Float16* wih1p = wbuf + (size_t)1*65536;
    const _Float16* wih2p = wbuf + (size_t)3*65536;

    // per-lane bias (this lane's gate only) and layer-0 input weight
    float bsv[3]; float w0v;
    {
        const float* bihs[3] = {bih0, bih1, bih2};
        const float* bhhs[3] = {bhh0, bhh1, bhh2};
        const int gate = q*HDIM + wv*16 + n16;
#pragma unroll
        for (int L = 0; L < 3; ++L) bsv[L] = bihs[L][gate] + bhhs[L][gate];
        w0v = Wih0[gate];
    }

    const float me = (q == 2) ? 2.0f : -1.0f;
    const float Aq = (q == 2) ? 1.0f : 0.0f;
    const float Bq = (q == 2) ? -2.0f : 1.0f;

    const int xgb = (q*HDIM + wv*16 + n16) * XGP;   // this lane's gate row base

    float cst[3] = {0.f, 0.f, 0.f};
    const float* xb = x + (size_t)b * TDIM;

    // ===== stage s: L0 on chunk s, L1 on s-1, L2 on s-2 =====
#pragma unroll 1
    for (int s = 0; s < 130; ++s) {
        const int par = s & 1;
        const bool act0 = (s < 128), act1 = (s >= 1) && (s < 129), act2 = (s >= 2);

        fast_barrier();   // prev stage's LDS reads done; proj/x_s may overwrite

        if (act0 && tid < 16) x_s[tid] = xb[s*16 + tid];
        // proj for L1 chunk s-1 from h0(chunk s-1) = hw[0][par^1] (written last stage)
        if (act1) PROJ(0, hw[0][par^1], wih1p);
        // proj for L2 chunk s-2 from h1(chunk s-2) = hw[1][par]
        if (act2) PROJ(1, hw[1][par], wih2p);

        fast_barrier();   // proj + x_s visible

#pragma unroll 1
        for (int tt = 0; tt < 16; ++tt) {
            if (tt) fast_barrier();
            // h(t-1) row / h(t) row per layer (cur-buf parity: L0,L2=par; L1=par^1)
            const _Float16* r0p = tt ? hw[0][par][tt-1]   : hw[0][par^1][15];
            _Float16*       q0p = hw[0][par][tt];
            const _Float16* r1p = tt ? hw[1][par^1][tt-1] : hw[1][par][15];
            _Float16*       q1p = hw[1][par^1][tt];
            const _Float16* r2p = tt ? hw[2][par][tt-1]   : hw[2][par^1][15];
            _Float16*       q2p = hw[2][par][tt];
            const float xt = x_s[tt];

            if (act0 && act1 && act2) {
                // steady state: one basic block so the scheduler interleaves all 3 layers
                STEPL(0, r0p, q0p, sel_ + fmaf(xt, w0v, bsv[0]));
                STEPL(1, r1p, q1p, sel_ + xg_s[0][xgb + tt] + bsv[1]);
                STEPL(2, r2p, q2p, sel_ + xg_s[1][xgb + tt] + bsv[2]);
            } else {
                if (act0) STEPL(0, r0p, q0p, sel_ + fmaf(xt, w0v, bsv[0]));
                if (act1) STEPL(1, r1p, q1p, sel_ + xg_s[0][xgb + tt] + bsv[1]);
                if (act2) STEPL(2, r2p, q2p, sel_ + xg_s[1][xgb + tt] + bsv[2]);
            }
        }
    }

    // ---- FC head: final h2 (t=2047) = hw[2][1][15] (chunk 127 done at stage 129) ----
    fast_barrier();
    if (tid < 64) {
        const float* w = fc1w + tid * HDIM;
        float sacc = fc1b[tid];
#pragma unroll
        for (int k = 0; k < HDIM; ++k) sacc += w[k] * (float)hw[2][1][15][k];
        z_s[tid] = fmaxf(sacc, 0.0f);
    }
    __syncthreads();
    if (tid < 5) {
        const float* w = fc2w + tid * 64;
        float sacc = fc2b[tid];
#pragma unroll
        for (int k = 0; k < 64; ++k) sacc += w[k] * z_s[k];
        out[b * 5 + tid] = sacc;
    }
}

extern "C" void kernel_launch(void* const* d_in, const int* in_sizes, int n_in,
                              void* d_out, int out_size, void* d_ws, size_t ws_size,
                              hipStream_t stream) {
    (void)in_sizes; (void)n_in; (void)out_size; (void)ws_size;
    const float* x    = (const float*)d_in[0];
    const float* Wih0 = (const float*)d_in[1];
    const float* Whh0 = (const float*)d_in[2];
    const float* bih0 = (const float*)d_in[3];
    const float* bhh0 = (const float*)d_in[4];
    const float* Wih1 = (const float*)d_in[5];
    const float* Whh1 = (const float*)d_in[6];
    const float* bih1 = (const float*)d_in[7];
    const float* bhh1 = (const float*)d_in[8];
    const float* Wih2 = (const float*)d_in[9];
    const float* Whh2 = (const float*)d_in[10];
    const float* bih2 = (const float*)d_in[11];
    const float* bhh2 = (const float*)d_in[12];
    const float* fc1w = (const float*)d_in[13];
    const float* fc1b = (const float*)d_in[14];
    const float* fc2w = (const float*)d_in[15];
    const float* fc2b = (const float*)d_in[16];
    float* out = (float*)d_out;

    _Float16* wbuf = (_Float16*)d_ws;   // fp16 weights (640 KB)

    hipLaunchKernelGGL(convert_w, dim3(1280), dim3(256), 0, stream,
                       Whh0, Wih1, Whh1, Wih2, Whh2, wbuf);
    hipLaunchKernelGGL(lstm3_kernel, dim3(BDIM), dim3(NT), 0, stream,
                       x, Wih0, bih0, bhh0, bih1, bhh1, bih2, bhh2,
                       fc1w, fc1b, fc2w, fc2b, out, wbuf);
}